// Round 5
// baseline (302.999 us; speedup 1.0000x reference)
//
#include <hip/hip_runtime.h>
#include <math.h>

#define B_ 32
#define Q_ 16
#define D_ 10
#define L_ 1000
#define E_ 300

#define NS_  4          // l-splits per (b,d)
#define TPS_ 250        // terms per split
#define T_   64         // terms per tile
#define NT_  4          // tiles per split (4*64 = 256 >= 250)
#define CH_  75         // float4 chunks per row (300 floats = 1200 B)
#define UNITS_     (T_ * CH_)   // 4800 16B units per tile
#define UNITS_PAD_ 4864         // 19 instr * 64 lanes * 4 waves
#define UPW_       1216         // units per wave = 19 * 64

#define AS1 __attribute__((address_space(1)))
#define AS3 __attribute__((address_space(3)))

// ---------------------------------------------------------------------------
// Kernel 1 (prep): per-batch query gather -> gate logits -> softmax,
// query norms, and score init with the affine constant C.
//   wq[b,q] = softmax(gate_logits)[b,q] * out_w * w2
//   nq[b,q] = ||emb[q_tok]||
//   score[b,d] = out_w*(w2*b1 + b2) + out_b      (atomics add onto this)
// ---------------------------------------------------------------------------
__global__ __launch_bounds__(256) void drmm_prep(
    const int* __restrict__ bq, const float* __restrict__ emb,
    const float* __restrict__ gate_w, const float* __restrict__ gate_b,
    const float* __restrict__ b1, const float* __restrict__ w2,
    const float* __restrict__ b2, const float* __restrict__ out_w,
    const float* __restrict__ out_b,
    float* __restrict__ wqBuf, float* __restrict__ nqBuf,
    float* __restrict__ score)
{
    const int b = blockIdx.x;
    const int tid = threadIdx.x;
    const int w = tid >> 6, lane = tid & 63;
    __shared__ float logits[Q_];

#pragma unroll
    for (int i = 0; i < 4; ++i) {
        const int q = w * 4 + i;                  // 4 waves x 4 -> q = 0..15
        const int tok = bq[b * Q_ + q];
        const float* row = emb + (size_t)tok * E_;
        float4 dv = *(const float4*)(row + 4 * lane);
        float4 gv = *(const float4*)(gate_w + 4 * lane);
        float pd = dv.x * gv.x + dv.y * gv.y + dv.z * gv.z + dv.w * gv.w;
        float ps = dv.x * dv.x + dv.y * dv.y + dv.z * dv.z + dv.w * dv.w;
        if (lane < 11) {
            float4 dv2 = *(const float4*)(row + 256 + 4 * lane);
            float4 gv2 = *(const float4*)(gate_w + 256 + 4 * lane);
            pd += dv2.x * gv2.x + dv2.y * gv2.y + dv2.z * gv2.z + dv2.w * gv2.w;
            ps += dv2.x * dv2.x + dv2.y * dv2.y + dv2.z * dv2.z + dv2.w * dv2.w;
        }
#pragma unroll
        for (int off = 32; off > 0; off >>= 1) {
            pd += __shfl_xor(pd, off);
            ps += __shfl_xor(ps, off);
        }
        if (lane == 0) {
            logits[q] = pd + gate_b[0];
            nqBuf[b * Q_ + q] = sqrtf(ps);
        }
    }
    __syncthreads();

    if (tid == 0) {
        float m = -1e30f;
        for (int q = 0; q < Q_; ++q) m = fmaxf(m, logits[q]);
        float e[Q_];
        float s = 0.f;
        for (int q = 0; q < Q_; ++q) { e[q] = expf(logits[q] - m); s += e[q]; }
        const float sc = out_w[0] * w2[0] / s;
        for (int q = 0; q < Q_; ++q) wqBuf[b * Q_ + q] = e[q] * sc;
    }
    if (tid < D_)
        score[b * D_ + tid] = out_w[0] * (w2[0] * b1[0] + b2[0]) + out_b[0];
}

// ---------------------------------------------------------------------------
// Kernel 2 (main): coalesced-staging version.
// Per tile of 64 doc terms: the 4 waves cooperatively DMA the 64 embedding
// rows into LDS via global_load_lds (dest is linear: unit u = row*75+chunk;
// per-lane global source address is computed from u via magic-div by 75).
// Each DMA instruction's 64 consecutive units span <=2 rows -> 2 long
// contiguous segments instead of 64 independent random 16B gathers ->
// lifts the per-CU address-rate ceiling that pinned R1/R3 at ~4-5 B/cyc/CU.
// Compute: each lane owns one term (row), each wave owns 4 queries (Q-split,
// no cross-lane combine). ds_read_b128 at byte lane*1200 + 16c -> 16B-column
// (75*lane + c) mod 8: evenly spread, conflict-free. Norm sumsq computed
// redundantly per wave from data already in registers.
// LDS: 4864*16 B tile + 64 tokens = ~78 KB -> 2 blocks/CU (8 waves/CU),
// each staging wave keeps ~19 KB in flight -> BW-saturating despite low
// occupancy. fp32 exact throughout.
// ---------------------------------------------------------------------------
__global__ __launch_bounds__(256, 2) void drmm_main(
    const int* __restrict__ bq, const int* __restrict__ bdocs,
    const float* __restrict__ emb, const float* __restrict__ w1,
    const float* __restrict__ wqBuf, const float* __restrict__ nqBuf,
    float* __restrict__ score)
{
    const int ls = blockIdx.x;   // l-split 0..3 (250 terms each)
    const int d  = blockIdx.y;
    const int b  = blockIdx.z;
    const int tid  = threadIdx.x;
    const int lane = tid & 63;
    const int w = __builtin_amdgcn_readfirstlane(tid >> 6);   // 0..3, uniform

    __shared__ float4 tile[UNITS_PAD_];   // 77,824 B
    __shared__ int    tokLDS[T_];
    __shared__ float  wsum[4];

    const float w10 = w1[0], w11 = w1[1], w12 = w1[2], w13 = w1[3], w14 = w1[4];

    // wave-local query state: 4 queries per wave (Q-split)
    const int q0 = w * 4;
    const float* qrow[4];
    float nqv[4], wqv[4];
#pragma unroll
    for (int j = 0; j < 4; ++j) {
        qrow[j] = emb + (size_t)bq[b * Q_ + q0 + j] * E_;
        nqv[j]  = nqBuf[b * Q_ + q0 + j];
        wqv[j]  = wqBuf[b * Q_ + q0 + j];
    }

    const int docBase = (b * D_ + d) * L_ + ls * TPS_;

    float total = 0.f;

    for (int t = 0; t < NT_; ++t) {
        // ---- stage tile t -------------------------------------------------
        // Tokens: every wave writes the full 64-entry table (identical
        // values -> benign race) so its own ds_reads are ordered by the
        // wave's program order without an extra barrier.
        const int tidx = min(t * T_ + lane, TPS_ - 1);
        tokLDS[lane] = bdocs[docBase + tidx];

        // 19 DMA instructions per wave; unit u = row*75 + chunk is linear
        // in LDS, so dest = uniform base + lane*16 exactly matches the HW.
#pragma unroll
        for (int i = 0; i < 19; ++i) {
            const int u = w * UPW_ + i * 64 + lane;
            const int row = (u * 55925) >> 22;        // == u/75 for u < 4864
            const int chunk = u - row * 75;
            const int rc = min(row, T_ - 1);          // pad-lane safe index
            const float* g = (u < UNITS_)
                ? emb + (size_t)tokLDS[rc] * E_ + chunk * 4
                : emb;                                // pad units: row 0 junk
            __builtin_amdgcn_global_load_lds(
                (const AS1 void*)g,
                (AS3 void*)&tile[w * UPW_ + i * 64],
                16, 0, 0);
        }
        __syncthreads();   // drains vmcnt: DMA complete before LDS reads

        // ---- compute tile t ----------------------------------------------
        const float4* trow = &tile[lane * CH_];
        float acc[4] = {0.f, 0.f, 0.f, 0.f};
        float sq = 0.f;
#pragma unroll 5
        for (int c = 0; c < CH_; ++c) {
            const float4 dv = trow[c];                 // ds_read_b128
            sq = fmaf(dv.x, dv.x, fmaf(dv.y, dv.y, fmaf(dv.z, dv.z, fmaf(dv.w, dv.w, sq))));
#pragma unroll
            for (int j = 0; j < 4; ++j) {
                const float4 qv = *(const float4*)(qrow[j] + 4 * c);  // uniform -> s_load
                acc[j] = fmaf(dv.w, qv.w, fmaf(dv.z, qv.z, fmaf(dv.y, qv.y, fmaf(dv.x, qv.x, acc[j]))));
            }
        }

        if (t * T_ + lane < TPS_) {                    // active terms only
            const float nd = sqrtf(sq);
#pragma unroll
            for (int j = 0; j < 4; ++j) {
                const float denom = fmaxf(nqv[j] * nd, 1e-8f);
                const float a = acc[j];
                // bins: [-1,-.5) [-.5,0) [0,.5) [.5,1) [1,1]; outside -> 0
                const float wv = (a < -denom)        ? 0.f
                               : (a < -0.5f * denom) ? w10
                               : (a < 0.f)           ? w11
                               : (a < 0.5f * denom)  ? w12
                               : (a < denom)         ? w13
                               : (a <= denom)        ? w14
                                                     : 0.f;
                total = fmaf(wqv[j], wv, total);
            }
        }
        __syncthreads();   // tile reads done before next tile's DMA overwrite
    }

    // block reduce: wave butterfly -> LDS -> one atomic
#pragma unroll
    for (int off = 32; off > 0; off >>= 1) total += __shfl_xor(total, off);
    if (lane == 0) wsum[w] = total;
    __syncthreads();
    if (tid == 0)
        atomicAdd(&score[b * D_ + d], wsum[0] + wsum[1] + wsum[2] + wsum[3]);
}

extern "C" void kernel_launch(void* const* d_in, const int* in_sizes, int n_in,
                              void* d_out, int out_size, void* d_ws, size_t ws_size,
                              hipStream_t stream)
{
    const int*   bq     = (const int*)d_in[0];
    const int*   bdocs  = (const int*)d_in[1];
    const float* emb    = (const float*)d_in[2];
    const float* gate_w = (const float*)d_in[3];
    const float* gate_b = (const float*)d_in[4];
    const float* w1     = (const float*)d_in[5];
    const float* b1     = (const float*)d_in[6];
    const float* w2     = (const float*)d_in[7];
    const float* b2     = (const float*)d_in[8];
    const float* out_w  = (const float*)d_in[9];
    const float* out_b  = (const float*)d_in[10];

    float* score = (float*)d_out;
    float* wqBuf = (float*)d_ws;         // 512 floats
    float* nqBuf = wqBuf + B_ * Q_;      // 512 floats  (ws usage: 4 KiB)

    drmm_prep<<<dim3(B_), dim3(256), 0, stream>>>(
        bq, emb, gate_w, gate_b, b1, w2, b2, out_w, out_b, wqBuf, nqBuf, score);

    drmm_main<<<dim3(NS_, D_, B_), dim3(256), 0, stream>>>(
        bq, bdocs, emb, w1, wqBuf, nqBuf, score);
}

// Round 7
// 219.718 us; speedup vs baseline: 1.3790x; 1.3790x over previous
//
#include <hip/hip_runtime.h>
#include <hip/hip_fp16.h>
#include <math.h>

#define VOCAB_ 50000
#define B_ 32
#define Q_ 16
#define D_ 10
#define L_ 1000
#define E_ 300

#define NS_  4          // l-splits per (b,d) -> 1280 blocks = 20 waves/CU
#define TPS_ 250        // terms per split (256 threads, 250 active)
#define RP_  304        // padded fp16 row stride (elems; 608 B, 16B-aligned)
#define G8_  38         // 8-elem groups per padded row (38*8 = 304)

typedef unsigned short u16x8 __attribute__((ext_vector_type(8)));

// ---------------------------------------------------------------------------
// Kernel 0 (cvt): fp32 embedding table -> fp16, row-padded to 304 elems
// (pad = 0 so padded elems contribute nothing to dot / sumsq).
// One block per vocab row; coalesced read + write. Runs every replay
// (~15 us) -- the doc-stream traffic it saves is ~190 MB per replay.
// ---------------------------------------------------------------------------
__global__ __launch_bounds__(256) void drmm_cvt(
    const float* __restrict__ emb, unsigned short* __restrict__ emb16)
{
    const int row = blockIdx.x;
    const int tid = threadIdx.x;
    const float* src = emb + (size_t)row * E_;
    unsigned short* dst = emb16 + (size_t)row * RP_;
    dst[tid] = (tid < E_) ? __half_as_ushort(__float2half_rn(src[tid]))
                          : (unsigned short)0;
    if (tid < RP_ - 256) {
        const int c = 256 + tid;
        dst[c] = (c < E_) ? __half_as_ushort(__float2half_rn(src[c]))
                          : (unsigned short)0;
    }
}

// ---------------------------------------------------------------------------
// Kernel 1 (prep): per-batch query gather -> gate logits -> softmax,
// query norms, and score init with the affine constant C.  (fp32 exact)
// ---------------------------------------------------------------------------
__global__ __launch_bounds__(256) void drmm_prep(
    const int* __restrict__ bq, const float* __restrict__ emb,
    const float* __restrict__ gate_w, const float* __restrict__ gate_b,
    const float* __restrict__ b1, const float* __restrict__ w2,
    const float* __restrict__ b2, const float* __restrict__ out_w,
    const float* __restrict__ out_b,
    float* __restrict__ wqBuf, float* __restrict__ nqBuf,
    float* __restrict__ score)
{
    const int b = blockIdx.x;
    const int tid = threadIdx.x;
    const int w = tid >> 6, lane = tid & 63;
    __shared__ float logits[Q_];

#pragma unroll
    for (int i = 0; i < 4; ++i) {
        const int q = w * 4 + i;
        const int tok = bq[b * Q_ + q];
        const float* row = emb + (size_t)tok * E_;
        float4 dv = *(const float4*)(row + 4 * lane);
        float4 gv = *(const float4*)(gate_w + 4 * lane);
        float pd = dv.x * gv.x + dv.y * gv.y + dv.z * gv.z + dv.w * gv.w;
        float ps = dv.x * dv.x + dv.y * dv.y + dv.z * dv.z + dv.w * dv.w;
        if (lane < 11) {
            float4 dv2 = *(const float4*)(row + 256 + 4 * lane);
            float4 gv2 = *(const float4*)(gate_w + 256 + 4 * lane);
            pd += dv2.x * gv2.x + dv2.y * gv2.y + dv2.z * gv2.z + dv2.w * gv2.w;
            ps += dv2.x * dv2.x + dv2.y * dv2.y + dv2.z * dv2.z + dv2.w * dv2.w;
        }
#pragma unroll
        for (int off = 32; off > 0; off >>= 1) {
            pd += __shfl_xor(pd, off);
            ps += __shfl_xor(ps, off);
        }
        if (lane == 0) {
            logits[q] = pd + gate_b[0];
            nqBuf[b * Q_ + q] = sqrtf(ps);
        }
    }
    __syncthreads();

    if (tid == 0) {
        float m = -1e30f;
        for (int q = 0; q < Q_; ++q) m = fmaxf(m, logits[q]);
        float e[Q_];
        float s = 0.f;
        for (int q = 0; q < Q_; ++q) { e[q] = expf(logits[q] - m); s += e[q]; }
        const float sc = out_w[0] * w2[0] / s;
        for (int q = 0; q < Q_; ++q) wqBuf[b * Q_ + q] = e[q] * sc;
    }
    if (tid < D_)
        score[b * D_ + tid] = out_w[0] * (w2[0] * b1[0] + b2[0]) + out_b[0];
}

// ---------------------------------------------------------------------------
// Kernel 2 (main): one lane per doc term, direct row streaming (the pattern
// that measured 2.4 TB/s continuous), with two byte-side fixes:
//   F16=true : doc rows read from the fp16 table (608 B vs 1200 B per row,
//              38 x 16B loads vs 75) -- halves delivered bytes AND halves
//              the in-order-vmcnt head-of-line latency chain per row.
//   q rows   : staged once per block in LDS (19.4 KB, fp32 exact); inner-
//              loop reads are wave-uniform addresses -> LDS broadcast,
//              removing the per-chunk scalar-cache (sL1) thrash.
// Bin epilogue compares dot vs k*denom (no division). One atomic per block.
// ---------------------------------------------------------------------------
template<bool F16>
__global__ __launch_bounds__(256, 4) void drmm_main(
    const int* __restrict__ bq, const int* __restrict__ bdocs,
    const float* __restrict__ emb, const unsigned short* __restrict__ emb16,
    const float* __restrict__ w1,
    const float* __restrict__ wqBuf, const float* __restrict__ nqBuf,
    float* __restrict__ score)
{
    const int ls = blockIdx.x;   // 0..3
    const int d  = blockIdx.y;
    const int b  = blockIdx.z;
    const int tid  = threadIdx.x;
    const int lane = tid & 63;
    const int w    = tid >> 6;

    // qt[q][76] float4: chunks 0..74 = query row, chunk 75 = zeros (pairs
    // with the fp16 row pad so group 37 contributes nothing spurious).
    __shared__ float4 qt[Q_ * 76];    // 19,456 B
    __shared__ float wsum[4];

    for (int u = tid; u < Q_ * 76; u += 256) {
        const int q = u / 76;
        const int c = u - q * 76;
        float4 v = make_float4(0.f, 0.f, 0.f, 0.f);
        if (c < 75)
            v = *(const float4*)(emb + (size_t)bq[b * Q_ + q] * E_ + 4 * c);
        qt[u] = v;
    }
    __syncthreads();

    // inactive lanes (tid 250..255) stream term 249's row; results discarded
    const int tok = bdocs[(b * D_ + d) * L_ + ls * TPS_ + min(tid, TPS_ - 1)];

    float acc[Q_];
#pragma unroll
    for (int q = 0; q < Q_; ++q) acc[q] = 0.f;
    float sqA = 0.f, sqB = 0.f;     // split sumsq: relaxes the serial chain

    if constexpr (F16) {
        const unsigned short* drow = emb16 + (size_t)tok * RP_;
#pragma unroll 10
        for (int g = 0; g < G8_; ++g) {
            const u16x8 dv = *(const u16x8*)(drow + 8 * g);   // 16B load
            const float d0 = __half2float(__ushort_as_half(dv[0]));
            const float d1 = __half2float(__ushort_as_half(dv[1]));
            const float d2 = __half2float(__ushort_as_half(dv[2]));
            const float d3 = __half2float(__ushort_as_half(dv[3]));
            const float d4 = __half2float(__ushort_as_half(dv[4]));
            const float d5 = __half2float(__ushort_as_half(dv[5]));
            const float d6 = __half2float(__ushort_as_half(dv[6]));
            const float d7 = __half2float(__ushort_as_half(dv[7]));
            sqA = fmaf(d0, d0, fmaf(d2, d2, fmaf(d4, d4, fmaf(d6, d6, sqA))));
            sqB = fmaf(d1, d1, fmaf(d3, d3, fmaf(d5, d5, fmaf(d7, d7, sqB))));
#pragma unroll
            for (int q = 0; q < Q_; ++q) {
                const float4 qa = qt[q * 76 + 2 * g];        // broadcast
                const float4 qb = qt[q * 76 + 2 * g + 1];    // broadcast
                float t0 = fmaf(d0, qa.x, fmaf(d1, qa.y,
                           fmaf(d2, qa.z, fmaf(d3, qa.w, acc[q]))));
                acc[q]   = fmaf(d4, qb.x, fmaf(d5, qb.y,
                           fmaf(d6, qb.z, fmaf(d7, qb.w, t0))));
            }
        }
    } else {
        const float* drow = emb + (size_t)tok * E_;
#pragma unroll 9
        for (int g = 0; g < 37; ++g) {
            const float4 a  = *(const float4*)(drow + 8 * g);
            const float4 c4 = *(const float4*)(drow + 8 * g + 4);
            sqA = fmaf(a.x, a.x, fmaf(a.z, a.z, fmaf(c4.x, c4.x, fmaf(c4.z, c4.z, sqA))));
            sqB = fmaf(a.y, a.y, fmaf(a.w, a.w, fmaf(c4.y, c4.y, fmaf(c4.w, c4.w, sqB))));
#pragma unroll
            for (int q = 0; q < Q_; ++q) {
                const float4 qa = qt[q * 76 + 2 * g];
                const float4 qb = qt[q * 76 + 2 * g + 1];
                float t0 = fmaf(a.x, qa.x, fmaf(a.y, qa.y,
                           fmaf(a.z, qa.z, fmaf(a.w, qa.w, acc[q]))));
                acc[q]   = fmaf(c4.x, qb.x, fmaf(c4.y, qb.y,
                           fmaf(c4.z, qb.z, fmaf(c4.w, qb.w, t0))));
            }
        }
        {   // tail: elems 296..299
            const float4 a = *(const float4*)(drow + 296);
            sqA = fmaf(a.x, a.x, fmaf(a.z, a.z, sqA));
            sqB = fmaf(a.y, a.y, fmaf(a.w, a.w, sqB));
#pragma unroll
            for (int q = 0; q < Q_; ++q) {
                const float4 qa = qt[q * 76 + 74];
                acc[q] = fmaf(a.x, qa.x, fmaf(a.y, qa.y,
                         fmaf(a.z, qa.z, fmaf(a.w, qa.w, acc[q]))));
            }
        }
    }

    float total = 0.f;
    if (tid < TPS_) {
        const float nd = sqrtf(sqA + sqB);
        const float w10 = w1[0], w11 = w1[1], w12 = w1[2],
                    w13 = w1[3], w14 = w1[4];
#pragma unroll
        for (int q = 0; q < Q_; ++q) {
            const float nqv = nqBuf[b * Q_ + q];   // uniform -> s_load
            const float wqv = wqBuf[b * Q_ + q];
            const float denom = fmaxf(nqv * nd, 1e-8f);
            const float a = acc[q];
            // bins: [-1,-.5) [-.5,0) [0,.5) [.5,1) [1,1]; outside -> 0
            const float wv = (a < -denom)        ? 0.f
                           : (a < -0.5f * denom) ? w10
                           : (a < 0.f)           ? w11
                           : (a < 0.5f * denom)  ? w12
                           : (a < denom)         ? w13
                           : (a <= denom)        ? w14
                                                 : 0.f;
            total = fmaf(wqv, wv, total);
        }
    }

#pragma unroll
    for (int off = 32; off > 0; off >>= 1) total += __shfl_xor(total, off);
    if (lane == 0) wsum[w] = total;
    __syncthreads();
    if (tid == 0)
        atomicAdd(&score[b * D_ + d], wsum[0] + wsum[1] + wsum[2] + wsum[3]);
}

extern "C" void kernel_launch(void* const* d_in, const int* in_sizes, int n_in,
                              void* d_out, int out_size, void* d_ws, size_t ws_size,
                              hipStream_t stream)
{
    const int*   bq     = (const int*)d_in[0];
    const int*   bdocs  = (const int*)d_in[1];
    const float* emb    = (const float*)d_in[2];
    const float* gate_w = (const float*)d_in[3];
    const float* gate_b = (const float*)d_in[4];
    const float* w1     = (const float*)d_in[5];
    const float* b1     = (const float*)d_in[6];
    const float* w2     = (const float*)d_in[7];
    const float* b2     = (const float*)d_in[8];
    const float* out_w  = (const float*)d_in[9];
    const float* out_b  = (const float*)d_in[10];

    float* score = (float*)d_out;
    float* wqBuf = (float*)d_ws;              // 512 floats
    float* nqBuf = wqBuf + B_ * Q_;           // 512 floats (first 4 KiB)

    const size_t e16_off   = 4096;
    const size_t e16_bytes = (size_t)VOCAB_ * RP_ * sizeof(unsigned short);
    const bool useF16 = ws_size >= e16_off + e16_bytes;
    unsigned short* emb16 = (unsigned short*)((char*)d_ws + e16_off);

    if (useF16)
        drmm_cvt<<<dim3(VOCAB_), dim3(256), 0, stream>>>(emb, emb16);

    drmm_prep<<<dim3(B_), dim3(256), 0, stream>>>(
        bq, emb, gate_w, gate_b, b1, w2, b2, out_w, out_b, wqBuf, nqBuf, score);

    if (useF16)
        drmm_main<true><<<dim3(NS_, D_, B_), dim3(256), 0, stream>>>(
            bq, bdocs, emb, emb16, w1, wqBuf, nqBuf, score);
    else
        drmm_main<false><<<dim3(NS_, D_, B_), dim3(256), 0, stream>>>(
            bq, bdocs, emb, emb16, w1, wqBuf, nqBuf, score);
}

// Round 13
// 187.985 us; speedup vs baseline: 1.6118x; 1.1688x over previous
//
#include <hip/hip_runtime.h>
#include <hip/hip_fp16.h>
#include <math.h>

#define VOCAB_ 50000
#define B_ 32
#define Q_ 16
#define D_ 10
#define L_ 1000
#define E_ 300

#define NS_  4          // l-splits per (b,d) -> 1280 blocks
#define TPS_ 250        // terms per split (256 threads, 250 active)
#define RP_  304        // padded fp16 row stride (elems; 608 B, 16B-aligned)
#define G8_  38         // 8-elem groups per padded row (38*8 = 304)
#define CVU_ (VOCAB_ * G8_)   // cvt work units (one 16B half8 store each)

typedef _Float16 half8 __attribute__((ext_vector_type(8)));
typedef _Float16 h2_t  __attribute__((ext_vector_type(2)));

// v_dot2_f32_f16: d = a.x*b.x + a.y*b.y + c (f32 accum). Guarded so a
// missing builtin degrades to the numerically-identical cvt+fma form
// (fp16 products are exact in f32) instead of failing the compile.
#if __has_builtin(__builtin_amdgcn_fdot2)
#define DOT2(a, b, c) __builtin_amdgcn_fdot2((a), (b), (c), false)
#else
#define DOT2(a, b, c) fmaf((float)(a)[0], (float)(b)[0], \
                      fmaf((float)(a)[1], (float)(b)[1], (c)))
#endif
#define SV2(v, i) __builtin_shufflevector((v), (v), 2*(i), 2*(i)+1)

// ---------------------------------------------------------------------------
// Kernel 0 (cvt): fp32 embedding -> fp16 table, row-padded to 304 elems
// (pad=0: contributes nothing to dot/sumsq). Vectorized: one thread per
// 8-elem group -> 2x float4 load + one 16B store (vs R7's 2B scalar
// stores, which were TA-rate-bound at ~15M store instrs).
// ---------------------------------------------------------------------------
__global__ __launch_bounds__(256) void drmm_cvt(
    const float* __restrict__ emb, _Float16* __restrict__ emb16)
{
    const int u = blockIdx.x * 256 + threadIdx.x;
    if (u >= CVU_) return;
    const int row = u / G8_;
    const int g   = u - row * G8_;
    const float* src = emb + (size_t)row * E_ + 8 * g;   // 16B-aligned
    half8 o;
    if (g < 37) {
        const float4 a = *(const float4*)src;
        const float4 c = *(const float4*)(src + 4);
        o[0] = (_Float16)a.x; o[1] = (_Float16)a.y;
        o[2] = (_Float16)a.z; o[3] = (_Float16)a.w;
        o[4] = (_Float16)c.x; o[5] = (_Float16)c.y;
        o[6] = (_Float16)c.z; o[7] = (_Float16)c.w;
    } else {                       // elems 296..299 + 4 zero pads
        const float4 a = *(const float4*)src;
        o[0] = (_Float16)a.x; o[1] = (_Float16)a.y;
        o[2] = (_Float16)a.z; o[3] = (_Float16)a.w;
        o[4] = (_Float16)0.f; o[5] = (_Float16)0.f;
        o[6] = (_Float16)0.f; o[7] = (_Float16)0.f;
    }
    *(half8*)(emb16 + (size_t)row * RP_ + 8 * g) = o;
}

// ---------------------------------------------------------------------------
// Kernel 1 (prep): per-batch query gather -> gate logits -> softmax,
// query norms, and score init with the affine constant.  (fp32 exact)
// ---------------------------------------------------------------------------
__global__ __launch_bounds__(256) void drmm_prep(
    const int* __restrict__ bq, const float* __restrict__ emb,
    const float* __restrict__ gate_w, const float* __restrict__ gate_b,
    const float* __restrict__ b1, const float* __restrict__ w2,
    const float* __restrict__ b2, const float* __restrict__ out_w,
    const float* __restrict__ out_b,
    float* __restrict__ wqBuf, float* __restrict__ nqBuf,
    float* __restrict__ score)
{
    const int b = blockIdx.x;
    const int tid = threadIdx.x;
    const int w = tid >> 6, lane = tid & 63;
    __shared__ float logits[Q_];

#pragma unroll
    for (int i = 0; i < 4; ++i) {
        const int q = w * 4 + i;
        const int tok = bq[b * Q_ + q];
        const float* row = emb + (size_t)tok * E_;
        float4 dv = *(const float4*)(row + 4 * lane);
        float4 gv = *(const float4*)(gate_w + 4 * lane);
        float pd = dv.x * gv.x + dv.y * gv.y + dv.z * gv.z + dv.w * gv.w;
        float ps = dv.x * dv.x + dv.y * dv.y + dv.z * dv.z + dv.w * dv.w;
        if (lane < 11) {
            float4 dv2 = *(const float4*)(row + 256 + 4 * lane);
            float4 gv2 = *(const float4*)(gate_w + 256 + 4 * lane);
            pd += dv2.x * gv2.x + dv2.y * gv2.y + dv2.z * gv2.z + dv2.w * gv2.w;
            ps += dv2.x * dv2.x + dv2.y * dv2.y + dv2.z * dv2.z + dv2.w * dv2.w;
        }
#pragma unroll
        for (int off = 32; off > 0; off >>= 1) {
            pd += __shfl_xor(pd, off);
            ps += __shfl_xor(ps, off);
        }
        if (lane == 0) {
            logits[q] = pd + gate_b[0];
            nqBuf[b * Q_ + q] = sqrtf(ps);
        }
    }
    __syncthreads();

    if (tid == 0) {
        float m = -1e30f;
        for (int q = 0; q < Q_; ++q) m = fmaxf(m, logits[q]);
        float e[Q_];
        float s = 0.f;
        for (int q = 0; q < Q_; ++q) { e[q] = expf(logits[q] - m); s += e[q]; }
        const float sc = out_w[0] * w2[0] / s;
        for (int q = 0; q < Q_; ++q) wqBuf[b * Q_ + q] = e[q] * sc;
    }
    if (tid < D_)
        score[b * D_ + tid] = out_w[0] * (w2[0] * b1[0] + b2[0]) + out_b[0];
}

// ---------------------------------------------------------------------------
// Kernel 2 (main, fp16): one lane per doc term, direct fp16 row streaming.
// Queries ALSO fp16, staged once per block in LDS (9.7 KB); inner loop is
// pure v_dot2_f32_f16: per 8-elem group = 1 global 16B load + 16 LDS b128
// broadcasts + 68 dot2 (vs R7's 144 VALU with 8 cvt). Bin epilogue
// compares dot vs k*denom (no division). One atomic per block.
// ---------------------------------------------------------------------------
__global__ __launch_bounds__(256, 4) void drmm_main_f16(
    const int* __restrict__ bq, const int* __restrict__ bdocs,
    const _Float16* __restrict__ emb16, const float* __restrict__ w1,
    const float* __restrict__ wqBuf, const float* __restrict__ nqBuf,
    float* __restrict__ score)
{
    const int ls = blockIdx.x;   // 0..3
    const int d  = blockIdx.y;
    const int b  = blockIdx.z;
    const int tid  = threadIdx.x;
    const int lane = tid & 63;
    const int w    = tid >> 6;

    __shared__ half8 qt[Q_ * G8_];    // 9,728 B  (qt[q*38+g])
    __shared__ float wsum[4];

    for (int u = tid; u < Q_ * G8_; u += 256) {
        const int q = u / G8_;
        const int g = u - q * G8_;
        qt[u] = *(const half8*)(emb16 + (size_t)bq[b * Q_ + q] * RP_ + 8 * g);
    }
    __syncthreads();

    // inactive lanes (tid 250..255) stream term 249's row; results discarded
    const int tok = bdocs[(b * D_ + d) * L_ + ls * TPS_ + min(tid, TPS_ - 1)];
    const _Float16* drow = emb16 + (size_t)tok * RP_;

    float acc[Q_];
#pragma unroll
    for (int q = 0; q < Q_; ++q) acc[q] = 0.f;
    float sq = 0.f;

#pragma unroll 8
    for (int g = 0; g < G8_; ++g) {
        const half8 dv = *(const half8*)(drow + 8 * g);   // 16B load
        const h2_t d0 = SV2(dv, 0), d1 = SV2(dv, 1),
                   d2 = SV2(dv, 2), d3 = SV2(dv, 3);
        sq = DOT2(d0, d0, DOT2(d1, d1, DOT2(d2, d2, DOT2(d3, d3, sq))));
#pragma unroll
        for (int q = 0; q < Q_; ++q) {
            const half8 qv = qt[q * G8_ + g];             // uniform: broadcast
            float t = DOT2(SV2(qv, 0), d0, acc[q]);
            t       = DOT2(SV2(qv, 1), d1, t);
            t       = DOT2(SV2(qv, 2), d2, t);
            acc[q]  = DOT2(SV2(qv, 3), d3, t);
        }
    }

    float total = 0.f;
    if (tid < TPS_) {
        const float nd = sqrtf(sq);
        const float w10 = w1[0], w11 = w1[1], w12 = w1[2],
                    w13 = w1[3], w14 = w1[4];
#pragma unroll
        for (int q = 0; q < Q_; ++q) {
            const float nqv = nqBuf[b * Q_ + q];   // uniform -> s_load
            const float wqv = wqBuf[b * Q_ + q];
            const float denom = fmaxf(nqv * nd, 1e-8f);
            const float a = acc[q];
            // bins: [-1,-.5) [-.5,0) [0,.5) [.5,1) [1,1]; outside -> 0
            const float wv = (a < -denom)        ? 0.f
                           : (a < -0.5f * denom) ? w10
                           : (a < 0.f)           ? w11
                           : (a < 0.5f * denom)  ? w12
                           : (a < denom)         ? w13
                           : (a <= denom)        ? w14
                                                 : 0.f;
            total = fmaf(wqv, wv, total);
        }
    }

#pragma unroll
    for (int off = 32; off > 0; off >>= 1) total += __shfl_xor(total, off);
    if (lane == 0) wsum[w] = total;
    __syncthreads();
    if (tid == 0)
        atomicAdd(&score[b * D_ + d], wsum[0] + wsum[1] + wsum[2] + wsum[3]);
}

// ---------------------------------------------------------------------------
// Kernel 2 fallback (fp32, used only if ws can't hold the fp16 table):
// R7's fp32 path -- direct fp32 row streaming + fp32 queries in LDS.
// ---------------------------------------------------------------------------
__global__ __launch_bounds__(256, 4) void drmm_main_f32(
    const int* __restrict__ bq, const int* __restrict__ bdocs,
    const float* __restrict__ emb, const float* __restrict__ w1,
    const float* __restrict__ wqBuf, const float* __restrict__ nqBuf,
    float* __restrict__ score)
{
    const int ls = blockIdx.x;
    const int d  = blockIdx.y;
    const int b  = blockIdx.z;
    const int tid  = threadIdx.x;
    const int lane = tid & 63;
    const int w    = tid >> 6;

    __shared__ float4 qt[Q_ * 76];    // chunks 0..74 row, 75 zeros
    __shared__ float wsum[4];

    for (int u = tid; u < Q_ * 76; u += 256) {
        const int q = u / 76;
        const int c = u - q * 76;
        float4 v = make_float4(0.f, 0.f, 0.f, 0.f);
        if (c < 75)
            v = *(const float4*)(emb + (size_t)bq[b * Q_ + q] * E_ + 4 * c);
        qt[u] = v;
    }
    __syncthreads();

    const int tok = bdocs[(b * D_ + d) * L_ + ls * TPS_ + min(tid, TPS_ - 1)];
    const float* drow = emb + (size_t)tok * E_;

    float acc[Q_];
#pragma unroll
    for (int q = 0; q < Q_; ++q) acc[q] = 0.f;
    float sqA = 0.f, sqB = 0.f;

#pragma unroll 9
    for (int g = 0; g < 37; ++g) {
        const float4 a  = *(const float4*)(drow + 8 * g);
        const float4 c4 = *(const float4*)(drow + 8 * g + 4);
        sqA = fmaf(a.x, a.x, fmaf(a.z, a.z, fmaf(c4.x, c4.x, fmaf(c4.z, c4.z, sqA))));
        sqB = fmaf(a.y, a.y, fmaf(a.w, a.w, fmaf(c4.y, c4.y, fmaf(c4.w, c4.w, sqB))));
#pragma unroll
        for (int q = 0; q < Q_; ++q) {
            const float4 qa = qt[q * 76 + 2 * g];
            const float4 qb = qt[q * 76 + 2 * g + 1];
            float t0 = fmaf(a.x, qa.x, fmaf(a.y, qa.y,
                       fmaf(a.z, qa.z, fmaf(a.w, qa.w, acc[q]))));
            acc[q]   = fmaf(c4.x, qb.x, fmaf(c4.y, qb.y,
                       fmaf(c4.z, qb.z, fmaf(c4.w, qb.w, t0))));
        }
    }
    {   // tail: elems 296..299
        const float4 a = *(const float4*)(drow + 296);
        sqA = fmaf(a.x, a.x, fmaf(a.z, a.z, sqA));
        sqB = fmaf(a.y, a.y, fmaf(a.w, a.w, sqB));
#pragma unroll
        for (int q = 0; q < Q_; ++q) {
            const float4 qa = qt[q * 76 + 74];
            acc[q] = fmaf(a.x, qa.x, fmaf(a.y, qa.y,
                     fmaf(a.z, qa.z, fmaf(a.w, qa.w, acc[q]))));
        }
    }

    float total = 0.f;
    if (tid < TPS_) {
        const float nd = sqrtf(sqA + sqB);
        const float w10 = w1[0], w11 = w1[1], w12 = w1[2],
                    w13 = w1[3], w14 = w1[4];
#pragma unroll
        for (int q = 0; q < Q_; ++q) {
            const float nqv = nqBuf[b * Q_ + q];
            const float wqv = wqBuf[b * Q_ + q];
            const float denom = fmaxf(nqv * nd, 1e-8f);
            const float a = acc[q];
            const float wv = (a < -denom)        ? 0.f
                           : (a < -0.5f * denom) ? w10
                           : (a < 0.f)           ? w11
                           : (a < 0.5f * denom)  ? w12
                           : (a < denom)         ? w13
                           : (a <= denom)        ? w14
                                                 : 0.f;
            total = fmaf(wqv, wv, total);
        }
    }

#pragma unroll
    for (int off = 32; off > 0; off >>= 1) total += __shfl_xor(total, off);
    if (lane == 0) wsum[w] = total;
    __syncthreads();
    if (tid == 0)
        atomicAdd(&score[b * D_ + d], wsum[0] + wsum[1] + wsum[2] + wsum[3]);
}

extern "C" void kernel_launch(void* const* d_in, const int* in_sizes, int n_in,
                              void* d_out, int out_size, void* d_ws, size_t ws_size,
                              hipStream_t stream)
{
    const int*   bq     = (const int*)d_in[0];
    const int*   bdocs  = (const int*)d_in[1];
    const float* emb    = (const float*)d_in[2];
    const float* gate_w = (const float*)d_in[3];
    const float* gate_b = (const float*)d_in[4];
    const float* w1     = (const float*)d_in[5];
    const float* b1     = (const float*)d_in[6];
    const float* w2     = (const float*)d_in[7];
    const float* b2     = (const float*)d_in[8];
    const float* out_w  = (const float*)d_in[9];
    const float* out_b  = (const float*)d_in[10];

    float* score = (float*)d_out;
    float* wqBuf = (float*)d_ws;              // 512 floats
    float* nqBuf = wqBuf + B_ * Q_;           // 512 floats (first 4 KiB)

    const size_t e16_off   = 4096;
    const size_t e16_bytes = (size_t)VOCAB_ * RP_ * sizeof(_Float16);
    const bool useF16 = ws_size >= e16_off + e16_bytes;
    _Float16* emb16 = (_Float16*)((char*)d_ws + e16_off);

    if (useF16)
        drmm_cvt<<<dim3((CVU_ + 255) / 256), dim3(256), 0, stream>>>(emb, emb16);

    drmm_prep<<<dim3(B_), dim3(256), 0, stream>>>(
        bq, emb, gate_w, gate_b, b1, w2, b2, out_w, out_b, wqBuf, nqBuf, score);

    if (useF16)
        drmm_main_f16<<<dim3(NS_, D_, B_), dim3(256), 0, stream>>>(
            bq, bdocs, emb16, w1, wqBuf, nqBuf, score);
    else
        drmm_main_f32<<<dim3(NS_, D_, B_), dim3(256), 0, stream>>>(
            bq, bdocs, emb, w1, wqBuf, nqBuf, score);
}

// Round 15
// 177.807 us; speedup vs baseline: 1.7041x; 1.0572x over previous
//
#include <hip/hip_runtime.h>
#include <hip/hip_fp16.h>
#include <math.h>

#define VOCAB_ 50000
#define B_ 32
#define Q_ 16
#define D_ 10
#define L_ 1000
#define E_ 300

#define NS_  4          // l-splits per (b,d) -> 1280 blocks
#define TPS_ 250        // terms per split (256 threads, 250 active)
#define RP_  320        // padded fp16 row stride: 640 B = 5 x 128B lines,
                        // rows 128B-aligned (base d_ws+4096 is 128B-aligned)
#define G8_  40         // 8-elem groups per padded row (40*8 = 320)
#define CVU_ (VOCAB_ * G8_)   // cvt work units (one 16B half8 store each)

typedef _Float16 half8 __attribute__((ext_vector_type(8)));
typedef _Float16 h2_t  __attribute__((ext_vector_type(2)));

// v_dot2_f32_f16: d = a.x*b.x + a.y*b.y + c (f32 accum). Guarded so a
// missing builtin degrades to the numerically-identical cvt+fma form
// (fp16 products are exact in f32) instead of failing the compile.
#if __has_builtin(__builtin_amdgcn_fdot2)
#define DOT2(a, b, c) __builtin_amdgcn_fdot2((a), (b), (c), false)
#else
#define DOT2(a, b, c) fmaf((float)(a)[0], (float)(b)[0], \
                      fmaf((float)(a)[1], (float)(b)[1], (c)))
#endif
#define SV2(v, i) __builtin_shufflevector((v), (v), 2*(i), 2*(i)+1)

// ---------------------------------------------------------------------------
// Kernel 0 (cvt): fp32 embedding -> fp16 table, row-padded to 320 elems
// (pad=0: contributes nothing to dot/sumsq). One thread per 8-elem group:
// 2x float4 load + one 16B store. Groups 38/39 are pure zero-pad (no read).
// ---------------------------------------------------------------------------
__global__ __launch_bounds__(256) void drmm_cvt(
    const float* __restrict__ emb, _Float16* __restrict__ emb16)
{
    const int u = blockIdx.x * 256 + threadIdx.x;
    if (u >= CVU_) return;
    const int row = u / G8_;
    const int g   = u - row * G8_;
    half8 o;
    if (g < 37) {
        const float* src = emb + (size_t)row * E_ + 8 * g;   // 16B-aligned
        const float4 a = *(const float4*)src;
        const float4 c = *(const float4*)(src + 4);
        o[0] = (_Float16)a.x; o[1] = (_Float16)a.y;
        o[2] = (_Float16)a.z; o[3] = (_Float16)a.w;
        o[4] = (_Float16)c.x; o[5] = (_Float16)c.y;
        o[6] = (_Float16)c.z; o[7] = (_Float16)c.w;
    } else if (g == 37) {          // elems 296..299 + 4 zero pads
        const float4 a = *(const float4*)(emb + (size_t)row * E_ + 296);
        o[0] = (_Float16)a.x; o[1] = (_Float16)a.y;
        o[2] = (_Float16)a.z; o[3] = (_Float16)a.w;
        o[4] = (_Float16)0.f; o[5] = (_Float16)0.f;
        o[6] = (_Float16)0.f; o[7] = (_Float16)0.f;
    } else {                       // groups 38,39: all zero (no read)
#pragma unroll
        for (int i = 0; i < 8; ++i) o[i] = (_Float16)0.f;
    }
    *(half8*)(emb16 + (size_t)row * RP_ + 8 * g) = o;
}

// ---------------------------------------------------------------------------
// Kernel 1 (prep): per-batch query gather -> gate logits -> softmax,
// query norms, and score init with the affine constant.  (fp32 exact)
// ---------------------------------------------------------------------------
__global__ __launch_bounds__(256) void drmm_prep(
    const int* __restrict__ bq, const float* __restrict__ emb,
    const float* __restrict__ gate_w, const float* __restrict__ gate_b,
    const float* __restrict__ b1, const float* __restrict__ w2,
    const float* __restrict__ b2, const float* __restrict__ out_w,
    const float* __restrict__ out_b,
    float* __restrict__ wqBuf, float* __restrict__ nqBuf,
    float* __restrict__ score)
{
    const int b = blockIdx.x;
    const int tid = threadIdx.x;
    const int w = tid >> 6, lane = tid & 63;
    __shared__ float logits[Q_];

#pragma unroll
    for (int i = 0; i < 4; ++i) {
        const int q = w * 4 + i;
        const int tok = bq[b * Q_ + q];
        const float* row = emb + (size_t)tok * E_;
        float4 dv = *(const float4*)(row + 4 * lane);
        float4 gv = *(const float4*)(gate_w + 4 * lane);
        float pd = dv.x * gv.x + dv.y * gv.y + dv.z * gv.z + dv.w * gv.w;
        float ps = dv.x * dv.x + dv.y * dv.y + dv.z * dv.z + dv.w * dv.w;
        if (lane < 11) {
            float4 dv2 = *(const float4*)(row + 256 + 4 * lane);
            float4 gv2 = *(const float4*)(gate_w + 256 + 4 * lane);
            pd += dv2.x * gv2.x + dv2.y * gv2.y + dv2.z * gv2.z + dv2.w * gv2.w;
            ps += dv2.x * dv2.x + dv2.y * dv2.y + dv2.z * dv2.z + dv2.w * dv2.w;
        }
#pragma unroll
        for (int off = 32; off > 0; off >>= 1) {
            pd += __shfl_xor(pd, off);
            ps += __shfl_xor(ps, off);
        }
        if (lane == 0) {
            logits[q] = pd + gate_b[0];
            nqBuf[b * Q_ + q] = sqrtf(ps);
        }
    }
    __syncthreads();

    if (tid == 0) {
        float m = -1e30f;
        for (int q = 0; q < Q_; ++q) m = fmaxf(m, logits[q]);
        float e[Q_];
        float s = 0.f;
        for (int q = 0; q < Q_; ++q) { e[q] = expf(logits[q] - m); s += e[q]; }
        const float sc = out_w[0] * w2[0] / s;
        for (int q = 0; q < Q_; ++q) wqBuf[b * Q_ + q] = e[q] * sc;
    }
    if (tid < D_)
        score[b * D_ + tid] = out_w[0] * (w2[0] * b1[0] + b2[0]) + out_b[0];
}

// ---------------------------------------------------------------------------
// Kernel 2 (main, fp16): one lane per doc term, direct fp16 row streaming.
// Rows are 640 B (5 aligned 128B lines; was 608 B straddling ~5.75 lines,
// -13% L2-miss bytes through the per-XCD L3 port -- the measured binding
// constraint at 1.45 TB/s). Queries fp16 in LDS (10.2 KB); inner loop is
// pure v_dot2_f32_f16. launch_bounds min-waves 2 (VGPR cap 128) for deeper
// compiler prefetch. Bin epilogue compares dot vs k*denom. One atomic/block.
// ---------------------------------------------------------------------------
__global__ __launch_bounds__(256, 2) void drmm_main_f16(
    const int* __restrict__ bq, const int* __restrict__ bdocs,
    const _Float16* __restrict__ emb16, const float* __restrict__ w1,
    const float* __restrict__ wqBuf, const float* __restrict__ nqBuf,
    float* __restrict__ score)
{
    const int ls = blockIdx.x;   // 0..3
    const int d  = blockIdx.y;
    const int b  = blockIdx.z;
    const int tid  = threadIdx.x;
    const int lane = tid & 63;
    const int w    = tid >> 6;

    __shared__ half8 qt[Q_ * G8_];    // 10,240 B  (qt[q*40+g])
    __shared__ float wsum[4];

    for (int u = tid; u < Q_ * G8_; u += 256) {
        const int q = u / G8_;
        const int g = u - q * G8_;
        qt[u] = *(const half8*)(emb16 + (size_t)bq[b * Q_ + q] * RP_ + 8 * g);
    }
    __syncthreads();

    // inactive lanes (tid 250..255) stream term 249's row; results discarded
    const int tok = bdocs[(b * D_ + d) * L_ + ls * TPS_ + min(tid, TPS_ - 1)];
    const _Float16* drow = emb16 + (size_t)tok * RP_;

    float acc[Q_];
#pragma unroll
    for (int q = 0; q < Q_; ++q) acc[q] = 0.f;
    float sq = 0.f;

#pragma unroll 8
    for (int g = 0; g < G8_; ++g) {
        const half8 dv = *(const half8*)(drow + 8 * g);   // 16B load
        const h2_t d0 = SV2(dv, 0), d1 = SV2(dv, 1),
                   d2 = SV2(dv, 2), d3 = SV2(dv, 3);
        sq = DOT2(d0, d0, DOT2(d1, d1, DOT2(d2, d2, DOT2(d3, d3, sq))));
#pragma unroll
        for (int q = 0; q < Q_; ++q) {
            const half8 qv = qt[q * G8_ + g];             // uniform: broadcast
            float t = DOT2(SV2(qv, 0), d0, acc[q]);
            t       = DOT2(SV2(qv, 1), d1, t);
            t       = DOT2(SV2(qv, 2), d2, t);
            acc[q]  = DOT2(SV2(qv, 3), d3, t);
        }
    }

    float total = 0.f;
    if (tid < TPS_) {
        const float nd = sqrtf(sq);
        const float w10 = w1[0], w11 = w1[1], w12 = w1[2],
                    w13 = w1[3], w14 = w1[4];
#pragma unroll
        for (int q = 0; q < Q_; ++q) {
            const float nqv = nqBuf[b * Q_ + q];   // uniform -> s_load
            const float wqv = wqBuf[b * Q_ + q];
            const float denom = fmaxf(nqv * nd, 1e-8f);
            const float a = acc[q];
            // bins: [-1,-.5) [-.5,0) [0,.5) [.5,1) [1,1]; outside -> 0
            const float wv = (a < -denom)        ? 0.f
                           : (a < -0.5f * denom) ? w10
                           : (a < 0.f)           ? w11
                           : (a < 0.5f * denom)  ? w12
                           : (a < denom)         ? w13
                           : (a <= denom)        ? w14
                                                 : 0.f;
            total = fmaf(wqv, wv, total);
        }
    }

#pragma unroll
    for (int off = 32; off > 0; off >>= 1) total += __shfl_xor(total, off);
    if (lane == 0) wsum[w] = total;
    __syncthreads();
    if (tid == 0)
        atomicAdd(&score[b * D_ + d], wsum[0] + wsum[1] + wsum[2] + wsum[3]);
}

// ---------------------------------------------------------------------------
// Kernel 2 fallback (fp32, used only if ws can't hold the fp16 table):
// direct fp32 row streaming + fp32 queries in LDS.
// ---------------------------------------------------------------------------
__global__ __launch_bounds__(256, 4) void drmm_main_f32(
    const int* __restrict__ bq, const int* __restrict__ bdocs,
    const float* __restrict__ emb, const float* __restrict__ w1,
    const float* __restrict__ wqBuf, const float* __restrict__ nqBuf,
    float* __restrict__ score)
{
    const int ls = blockIdx.x;
    const int d  = blockIdx.y;
    const int b  = blockIdx.z;
    const int tid  = threadIdx.x;
    const int lane = tid & 63;
    const int w    = tid >> 6;

    __shared__ float4 qt[Q_ * 76];    // chunks 0..74 row, 75 zeros
    __shared__ float wsum[4];

    for (int u = tid; u < Q_ * 76; u += 256) {
        const int q = u / 76;
        const int c = u - q * 76;
        float4 v = make_float4(0.f, 0.f, 0.f, 0.f);
        if (c < 75)
            v = *(const float4*)(emb + (size_t)bq[b * Q_ + q] * E_ + 4 * c);
        qt[u] = v;
    }
    __syncthreads();

    const int tok = bdocs[(b * D_ + d) * L_ + ls * TPS_ + min(tid, TPS_ - 1)];
    const float* drow = emb + (size_t)tok * E_;

    float acc[Q_];
#pragma unroll
    for (int q = 0; q < Q_; ++q) acc[q] = 0.f;
    float sqA = 0.f, sqB = 0.f;

#pragma unroll 9
    for (int g = 0; g < 37; ++g) {
        const float4 a  = *(const float4*)(drow + 8 * g);
        const float4 c4 = *(const float4*)(drow + 8 * g + 4);
        sqA = fmaf(a.x, a.x, fmaf(a.z, a.z, fmaf(c4.x, c4.x, fmaf(c4.z, c4.z, sqA))));
        sqB = fmaf(a.y, a.y, fmaf(a.w, a.w, fmaf(c4.y, c4.y, fmaf(c4.w, c4.w, sqB))));
#pragma unroll
        for (int q = 0; q < Q_; ++q) {
            const float4 qa = qt[q * 76 + 2 * g];
            const float4 qb = qt[q * 76 + 2 * g + 1];
            float t0 = fmaf(a.x, qa.x, fmaf(a.y, qa.y,
                       fmaf(a.z, qa.z, fmaf(a.w, qa.w, acc[q]))));
            acc[q]   = fmaf(c4.x, qb.x, fmaf(c4.y, qb.y,
                       fmaf(c4.z, qb.z, fmaf(c4.w, qb.w, t0))));
        }
    }
    {   // tail: elems 296..299
        const float4 a = *(const float4*)(drow + 296);
        sqA = fmaf(a.x, a.x, fmaf(a.z, a.z, sqA));
        sqB = fmaf(a.y, a.y, fmaf(a.w, a.w, sqB));
#pragma unroll
        for (int q = 0; q < Q_; ++q) {
            const float4 qa = qt[q * 76 + 74];
            acc[q] = fmaf(a.x, qa.x, fmaf(a.y, qa.y,
                     fmaf(a.z, qa.z, fmaf(a.w, qa.w, acc[q]))));
        }
    }

    float total = 0.f;
    if (tid < TPS_) {
        const float nd = sqrtf(sqA + sqB);
        const float w10 = w1[0], w11 = w1[1], w12 = w1[2],
                    w13 = w1[3], w14 = w1[4];
#pragma unroll
        for (int q = 0; q < Q_; ++q) {
            const float nqv = nqBuf[b * Q_ + q];
            const float wqv = wqBuf[b * Q_ + q];
            const float denom = fmaxf(nqv * nd, 1e-8f);
            const float a = acc[q];
            const float wv = (a < -denom)        ? 0.f
                           : (a < -0.5f * denom) ? w10
                           : (a < 0.f)           ? w11
                           : (a < 0.5f * denom)  ? w12
                           : (a < denom)         ? w13
                           : (a <= denom)        ? w14
                                                 : 0.f;
            total = fmaf(wqv, wv, total);
        }
    }

#pragma unroll
    for (int off = 32; off > 0; off >>= 1) total += __shfl_xor(total, off);
    if (lane == 0) wsum[w] = total;
    __syncthreads();
    if (tid == 0)
        atomicAdd(&score[b * D_ + d], wsum[0] + wsum[1] + wsum[2] + wsum[3]);
}

extern "C" void kernel_launch(void* const* d_in, const int* in_sizes, int n_in,
                              void* d_out, int out_size, void* d_ws, size_t ws_size,
                              hipStream_t stream)
{
    const int*   bq     = (const int*)d_in[0];
    const int*   bdocs  = (const int*)d_in[1];
    const float* emb    = (const float*)d_in[2];
    const float* gate_w = (const float*)d_in[3];
    const float* gate_b = (const float*)d_in[4];
    const float* w1     = (const float*)d_in[5];
    const float* b1     = (const float*)d_in[6];
    const float* w2     = (const float*)d_in[7];
    const float* b2     = (const float*)d_in[8];
    const float* out_w  = (const float*)d_in[9];
    const float* out_b  = (const float*)d_in[10];

    float* score = (float*)d_out;
    float* wqBuf = (float*)d_ws;              // 512 floats
    float* nqBuf = wqBuf + B_ * Q_;           // 512 floats (first 4 KiB)

    const size_t e16_off   = 4096;
    const size_t e16_bytes = (size_t)VOCAB_ * RP_ * sizeof(_Float16);  // 32 MB
    const bool useF16 = ws_size >= e16_off + e16_bytes;
    _Float16* emb16 = (_Float16*)((char*)d_ws + e16_off);

    if (useF16)
        drmm_cvt<<<dim3((CVU_ + 255) / 256), dim3(256), 0, stream>>>(emb, emb16);

    drmm_prep<<<dim3(B_), dim3(256), 0, stream>>>(
        bq, emb, gate_w, gate_b, b1, w2, b2, out_w, out_b, wqBuf, nqBuf, score);

    if (useF16)
        drmm_main_f16<<<dim3(NS_, D_, B_), dim3(256), 0, stream>>>(
            bq, bdocs, emb16, w1, wqBuf, nqBuf, score);
    else
        drmm_main_f32<<<dim3(NS_, D_, B_), dim3(256), 0, stream>>>(
            bq, bdocs, emb, w1, wqBuf, nqBuf, score);
}